// Round 10
// baseline (338.411 us; speedup 1.0000x reference)
//
#include <hip/hip_runtime.h>
#include <hip/hip_cooperative_groups.h>
#include <hip/hip_bf16.h>
#include <math.h>

namespace cg = cooperative_groups;

#define L 128
#define B 4
#define H 768
#define LN_EPS 1e-5f
#define XROWS 272            // [p1:0..127 | p2:128..255 | pg:256 | ones:257 | 0:258..271]
#define DSTRIDE 73984        // 272*272

typedef __attribute__((ext_vector_type(8))) short short8;
typedef __attribute__((ext_vector_type(4))) float f32x4;

static __device__ __forceinline__ unsigned f2bfu(float f) {
    unsigned u = __float_as_uint(f);
    return (u + 0x7FFFu + ((u >> 16) & 1u)) >> 16;
}
static __device__ __forceinline__ uint2 pk4(float4 v) {
    uint2 o;
    o.x = f2bfu(v.x) | (f2bfu(v.y) << 16);
    o.y = f2bfu(v.z) | (f2bfu(v.w) << 16);
    return o;
}
static __device__ __forceinline__ unsigned short f2b(float f) {
    union { __hip_bfloat16 h; unsigned short u; } cv;
    cv.h = __float2bfloat16(f);
    return cv.u;
}
static __device__ __forceinline__ float4 unpk4(uint2 p) {
    return make_float4(__uint_as_float(p.x << 16),
                       __uint_as_float(p.x & 0xffff0000u),
                       __uint_as_float(p.y << 16),
                       __uint_as_float(p.y & 0xffff0000u));
}
static __device__ __forceinline__ unsigned fkey(float x) {
    unsigned u = __float_as_uint(x);
    return (u >> 31) ? ~u : (u | 0x80000000u);
}

template<int KS>
static __device__ __forceinline__ void gemm_tile(const unsigned short* __restrict__ ap,
                                                 const unsigned short* __restrict__ wr,
                                                 f32x4 acc[2][2]) {
#pragma unroll 4
    for (int s = 0; s < KS; s++) {
        short8 a0 = *(const short8*)(ap + (size_t)s * 512);
        short8 a1 = *(const short8*)(ap + (size_t)(48 + s) * 512);
        short8 w0 = *(const short8*)(wr + (size_t)s * 512);
        short8 w1 = *(const short8*)(wr + (size_t)(KS + s) * 512);
        acc[0][0] = __builtin_amdgcn_mfma_f32_16x16x32_bf16(a0, w0, acc[0][0], 0, 0, 0);
        acc[0][1] = __builtin_amdgcn_mfma_f32_16x16x32_bf16(a0, w1, acc[0][1], 0, 0, 0);
        acc[1][0] = __builtin_amdgcn_mfma_f32_16x16x32_bf16(a1, w0, acc[1][0], 0, 0, 0);
        acc[1][1] = __builtin_amdgcn_mfma_f32_16x16x32_bf16(a1, w1, acc[1][1], 0, 0, 0);
    }
}

// ---------------------------------------------------------------------------
// mega: all 5 stages in one cooperative kernel, grid.sync() between stages.
// ---------------------------------------------------------------------------
__global__ __launch_bounds__(256, 4) void mega(const float* __restrict__ h_re,
                                               const float* __restrict__ h_share,
                                               const float* __restrict__ r_w,
                                               const float* __restrict__ hid_w,
                                               const float* __restrict__ rel_w,
                                               const float* __restrict__ mask,
                                               const float* __restrict__ r_b,
                                               const float* __restrict__ hid_b,
                                               const float* __restrict__ ln_g,
                                               const float* __restrict__ ln_b,
                                               const float* __restrict__ rel_b,
                                               unsigned short* __restrict__ apack,
                                               unsigned short* __restrict__ wpackA,
                                               unsigned short* __restrict__ wpackB,
                                               unsigned short* __restrict__ rwb16,
                                               unsigned short* __restrict__ xb16,
                                               unsigned int* __restrict__ gmax,
                                               float* __restrict__ D,
                                               float* __restrict__ out) {
    __shared__ __align__(16) unsigned char smem[25088];   // 16*780*2 = 24960 (+pad)
    __shared__ float smu[16], srs[16];
    int bx = blockIdx.x, nb = gridDim.x;
    int tid = threadIdx.x, lane = tid & 63, wave = tid >> 6;
    cg::grid_group grid = cg::this_grid();

    // ================= phase 0: conv / pack (bf16) =================
    for (int t = bx * 256 + tid; t < 402816; t += nb * 256) {
        if (t < 98304) {                          // apack: Acat=[h_share|h_re]
            int m = t / 192, oct = t % 192, k = oct * 8;
            const float* src = (k < 768) ? (h_share + (size_t)m * 768 + k)
                                         : (h_re + (size_t)m * 768 + k - 768);
            float4 x = *(const float4*)src, y = *(const float4*)(src + 4);
            int mt = m >> 4, lr = m & 15, ks = k >> 5, lq = (k >> 3) & 3;
            uint2* dst = (uint2*)(apack + (((size_t)mt * 48 + ks) * 64 + lq * 16 + lr) * 8);
            dst[0] = pk4(x); dst[1] = pk4(y);
        } else if (t < 245760) {                  // wpackA: r_w rows
            int t2 = t - 98304;
            int n = t2 / 192, oct = t2 % 192, k = oct * 8;
            const float* src = r_w + (size_t)n * 1536 + k;
            float4 x = *(const float4*)src, y = *(const float4*)(src + 4);
            int nt = n >> 4, lr = n & 15, ks = k >> 5, lq = (k >> 3) & 3;
            uint2* dst = (uint2*)(wpackA + (((size_t)nt * 48 + ks) * 64 + lq * 16 + lr) * 8);
            dst[0] = pk4(x); dst[1] = pk4(y);
        } else if (t < 393216) {                  // wpackB: hid_w rows (w1|w2)
            int t3 = t - 245760;
            int n = t3 / 96, oct = t3 % 96, k = oct * 8;
            int half = (n >= 768) ? 1 : 0;
            const float* src = hid_w + (size_t)(n - half * 768) * 2304 + half * 768 + k;
            float4 x = *(const float4*)src, y = *(const float4*)(src + 4);
            int nt = n >> 4, lr = n & 15, ks = k >> 5, lq = (k >> 3) & 3;
            uint2* dst = (uint2*)(wpackB + (((size_t)nt * 24 + ks) * 64 + lq * 16 + lr) * 8);
            dst[0] = pk4(x); dst[1] = pk4(y);
        } else if (t < 396288) {                  // rwb16: [2 nt][24 ks][64 lane][8]
            int t4 = t - 393216;
            int nt = t4 / 1536, ks = (t4 / 64) % 24, l = t4 & 63;
            int row = nt * 16 + (l & 15);
            int k = ks * 32 + (l >> 4) * 8;
            uint2 o0 = make_uint2(0u, 0u), o1 = o0;
            if (row < 24) {
                const float* src = rel_w + (size_t)row * 768 + k;
                o0 = pk4(*(const float4*)src);
                o1 = pk4(*(const float4*)(src + 4));
            }
            uint2* dst = (uint2*)(rwb16 + (size_t)t4 * 8);
            dst[0] = o0; dst[1] = o1;
        } else if (t < 402048) {                  // X tail rows 257..271
            int t5 = t - 396288;
            int b = t5 / 1440, rem = t5 % 1440, row = 257 + rem / 96, oct = rem % 96;
            unsigned val = (row == 257) ? 0x3F803F80u : 0u;
            uint2* dst = (uint2*)(xb16 + ((size_t)b * XROWS + row) * 768 + oct * 8);
            dst[0] = make_uint2(val, val); dst[1] = make_uint2(val, val);
        } else {                                  // gmax zero
            int t6 = t - 402048;
            ((uint4*)gmax)[t6] = make_uint4(0u, 0u, 0u, 0u);
        }
    }
    grid.sync();

    // ================= phase 1: both GEMMs (wave tiles) =================
    for (int id = wave * nb + bx; id < 1152; id += 4 * nb) {
        int lq = lane >> 4, lr = lane & 15;
        f32x4 acc[2][2] = {{{0.f,0.f,0.f,0.f},{0.f,0.f,0.f,0.f}},
                           {{0.f,0.f,0.f,0.f},{0.f,0.f,0.f,0.f}}};
        if (id < 384) {
            int mt0 = (id / 24) * 2, nt0 = (id % 24) * 2;
            const unsigned short* ap = apack + (size_t)mt0 * 48 * 512 + lane * 8;
            const unsigned short* wr = wpackA + (size_t)nt0 * 48 * 512 + lane * 8;
            gemm_tile<48>(ap, wr, acc);
#pragma unroll
            for (int ni = 0; ni < 2; ni++)
#pragma unroll
                for (int q = 0; q < 4; q++) {
                    float mx = fmaxf(acc[0][ni][q], acc[1][ni][q]);
                    mx = fmaxf(mx, __shfl_xor(mx, 16, 64));
                    mx = fmaxf(mx, __shfl_xor(mx, 32, 64));
                    if (lq == 0) {
                        int n = (nt0 + ni) * 16 + lr;
                        atomicMax(&gmax[q * 768 + n], fkey(mx));
                    }
                }
        } else {
            int id2 = id - 384;
            int mt0 = (id2 / 48) * 2, nt0 = (id2 % 48) * 2;
            const unsigned short* ap = apack + ((size_t)mt0 * 48 + 24) * 512 + lane * 8;
            const unsigned short* wr = wpackB + (size_t)nt0 * 24 * 512 + lane * 8;
            gemm_tile<24>(ap, wr, acc);
#pragma unroll
            for (int mi = 0; mi < 2; mi++)
#pragma unroll
                for (int ni = 0; ni < 2; ni++)
#pragma unroll
                    for (int q = 0; q < 4; q++) {
                        int m = (mt0 + mi) * 16 + lq * 4 + q;
                        int n = (nt0 + ni) * 16 + lr;
                        int b = m & 3, l = m >> 2;
                        size_t row = (n < 768) ? (size_t)l : (size_t)(128 + l);
                        int col = (n < 768) ? n : n - 768;
                        xb16[((size_t)b * XROWS + row) * 768 + col] = f2b(acc[mi][ni][q]);
                    }
        }
    }
    grid.sync();

    // ================= phase 2: max decode + tanh + pg =================
    for (int task = bx; task < 48; task += nb) {
        int kt = task % 12, b = task / 12;
        float* sg = (float*)smem;                    // 768 f32
        float (*sp)[64] = (float (*)[64])(smem + 3072);
        for (int v = tid; v < 768; v += 256) {
            unsigned key = gmax[b * 768 + v];
            unsigned bits = (key & 0x80000000u) ? (key & 0x7FFFFFFFu) : ~key;
            sg[v] = tanhf(__uint_as_float(bits) + r_b[v]);
        }
        __syncthreads();
        int kk = tid & 63, hc = tid >> 6;
        int k = kt * 64 + kk;
        const float4* w4 = (const float4*)hid_w;
        const float4* g4 = (const float4*)sg;
        float acc = 0.f;
        for (int h = hc * 48; h < hc * 48 + 48; h++) {
            float4 gv = g4[h];
            float4 wv = w4[(size_t)k * 576 + 384 + h];
            acc += gv.x * wv.x + gv.y * wv.y + gv.z * wv.z + gv.w * wv.w;
        }
        sp[hc][kk] = acc;
        __syncthreads();
        if (hc == 0) {
            float pgv = sp[0][kk] + sp[1][kk] + sp[2][kk] + sp[3][kk] + hid_b[k];
            xb16[((size_t)b * XROWS + 256) * 768 + k] = f2b(pgv);
        }
        __syncthreads();
    }
    grid.sync();

    // ================= phase 3: Gram D = X.X^T (wave tiles) =================
    for (int t = wave * nb + bx; t < 1156; t += 4 * nb) {
        int it = t % 17, jt = (t / 17) % 17, b = t / 289;
        int lq = lane >> 4, lr = lane & 15;
        const unsigned short* ar = xb16 + ((size_t)b * XROWS + it * 16 + lr) * 768 + lq * 8;
        const unsigned short* wr = xb16 + ((size_t)b * XROWS + jt * 16 + lr) * 768 + lq * 8;
        f32x4 acc = {0.f, 0.f, 0.f, 0.f};
#pragma unroll 8
        for (int s = 0; s < 24; s++) {
            short8 a = *(const short8*)(ar + s * 32);
            short8 w = *(const short8*)(wr + s * 32);
            acc = __builtin_amdgcn_mfma_f32_16x16x32_bf16(a, w, acc, 0, 0, 0);
        }
        float* Db = D + (size_t)b * DSTRIDE;
#pragma unroll
        for (int q = 0; q < 4; q++)
            Db[(size_t)(it * 16 + lq * 4 + q) * XROWS + jt * 16 + lr] = acc[q];
    }
    grid.sync();

    // ================= phase 4: LN + ELU + rel projection =================
    const float4* lg4 = (const float4*)ln_g;
    const float4* lb4 = (const float4*)ln_b;
    for (int t = bx; t < 4096; t += nb) {
        int i = t & 127, b = (t >> 7) & 3, jg = t >> 9;
        int j0 = jg * 16;
        unsigned short (*zls)[780] = (unsigned short (*)[780])smem;

        if (tid < 16) {
            const float* Db = D + (size_t)b * DSTRIDE;
            int vr = 128 + j0 + tid;
            float Su1 = Db[(size_t)i * XROWS + 257];
            float Su2 = Db[(size_t)i * XROWS + i];
            float up  = Db[(size_t)i * XROWS + 256];
            float Sp1 = Db[(size_t)256 * XROWS + 257];
            float Sp2 = Db[(size_t)256 * XROWS + 256];
            float Sv1 = Db[(size_t)vr * XROWS + 257];
            float Sv2 = Db[(size_t)vr * XROWS + vr];
            float Dij = Db[(size_t)i * XROWS + vr];
            float cvj = Db[(size_t)vr * XROWS + 256];
            float s1 = Su1 + Sp1 + Sv1;
            float s2 = Su2 + Sp2 + Sv2 + 2.f * (Dij + up + cvj);
            float mu = s1 * (1.f / 768.f);
            smu[tid] = mu;
            srs[tid] = rsqrtf(s2 * (1.f / 768.f) - mu * mu + LN_EPS);
        }
        const uint2* ur = (const uint2*)(xb16 + ((size_t)b * XROWS + i) * 768);
        const uint2* pr = (const uint2*)(xb16 + ((size_t)b * XROWS + 256) * 768);
        float4 t1[3], gg[3], bb[3];
#pragma unroll
        for (int s = 0; s < 3; s++) {
            int c = lane + 64 * s;
            float4 x = unpk4(ur[c]), y = unpk4(pr[c]);
            t1[s] = make_float4(x.x + y.x, x.y + y.y, x.z + y.z, x.w + y.w);
            gg[s] = lg4[c];
            bb[s] = lb4[c];
        }
        __syncthreads();

#pragma unroll
        for (int jj = 0; jj < 4; jj++) {
            int j = wave * 4 + jj;
            float mu = smu[j], rs = srs[j];
            const uint2* vr2 = (const uint2*)(xb16 + ((size_t)b * XROWS + 128 + j0 + j) * 768);
            uint2* zrow = (uint2*)&zls[j][0];
#pragma unroll
            for (int s = 0; s < 3; s++) {
                int c = lane + 64 * s;
                float4 vv = unpk4(vr2[c]);
                float A0 = rs * gg[s].x, A1 = rs * gg[s].y, A2 = rs * gg[s].z, A3 = rs * gg[s].w;
                float C0 = fmaf(-mu, A0, bb[s].x), C1 = fmaf(-mu, A1, bb[s].y);
                float C2 = fmaf(-mu, A2, bb[s].z), C3 = fmaf(-mu, A3, bb[s].w);
                float z0 = fmaf(t1[s].x + vv.x, A0, C0);
                float z1 = fmaf(t1[s].y + vv.y, A1, C1);
                float z2 = fmaf(t1[s].z + vv.z, A2, C2);
                float z3 = fmaf(t1[s].w + vv.w, A3, C3);
                z0 = fmaxf(z0, __expf(fminf(z0, 0.f)) - 1.f);
                z1 = fmaxf(z1, __expf(fminf(z1, 0.f)) - 1.f);
                z2 = fmaxf(z2, __expf(fminf(z2, 0.f)) - 1.f);
                z3 = fmaxf(z3, __expf(fminf(z3, 0.f)) - 1.f);
                uint2 o;
                o.x = (unsigned)f2b(z0) | ((unsigned)f2b(z1) << 16);
                o.y = (unsigned)f2b(z2) | ((unsigned)f2b(z3) << 16);
                zrow[c] = o;
            }
        }
        __syncthreads();

        // rel MFMA: wave = (nt = w&1, kt2 = w>>1), 12 K-steps each
        int lq = lane >> 4, lr = lane & 15;
        int nt = wave & 1, kt2 = wave >> 1;
        f32x4 acc = {0.f, 0.f, 0.f, 0.f};
#pragma unroll
        for (int st = 0; st < 12; st++) {
            int ks = kt2 * 12 + st;
            short8 a  = *(const short8*)&zls[lr][ks * 32 + lq * 8];
            short8 bf = *(const short8*)(rwb16 + ((size_t)(nt * 24 + ks) * 64 + lane) * 8);
            acc = __builtin_amdgcn_mfma_f32_16x16x32_bf16(a, bf, acc, 0, 0, 0);
        }
        __syncthreads();
        float* pacc = (float*)smem;
#pragma unroll
        for (int q = 0; q < 4; q++)
            pacc[(kt2 * 2 + nt) * 256 + (lq * 4 + q) * 16 + lr] = acc[q];
        __syncthreads();

        int jj2 = tid >> 4, c = tid & 15;
        int jgl = j0 + jj2;
        float mval = mask[i * 4 + b] * mask[jgl * 4 + b];
        size_t ob = ((size_t)(i * 128 + jgl) * 4 + b) * 24;
        float v0 = pacc[jj2 * 16 + c] + pacc[512 + jj2 * 16 + c];
        out[ob + c] = mval / (1.f + __expf(-(v0 + rel_b[c])));
        if (c < 8) {
            float v1 = pacc[256 + jj2 * 16 + c] + pacc[768 + jj2 * 16 + c];
            out[ob + 16 + c] = mval / (1.f + __expf(-(v1 + rel_b[16 + c])));
        }
        __syncthreads();
    }
}

// ---------------------------------------------------------------------------
extern "C" void kernel_launch(void* const* d_in, const int* in_sizes, int n_in,
                              void* d_out, int out_size, void* d_ws, size_t ws_size,
                              hipStream_t stream) {
    const float* h_re    = (const float*)d_in[0];
    const float* h_share = (const float*)d_in[1];
    const float* mask    = (const float*)d_in[2];
    const float* r_w     = (const float*)d_in[3];
    const float* r_b     = (const float*)d_in[4];
    const float* hid_w   = (const float*)d_in[5];
    const float* hid_b   = (const float*)d_in[6];
    const float* ln_g    = (const float*)d_in[7];
    const float* ln_b    = (const float*)d_in[8];
    const float* rel_w   = (const float*)d_in[9];
    const float* rel_b   = (const float*)d_in[10];
    float* out = (float*)d_out;

    float* ws = (float*)d_ws;
    unsigned short* apack  = (unsigned short*)(ws);             // 393216 f
    unsigned short* wpackA = (unsigned short*)(ws + 393216);    // 589824 f
    unsigned short* wpackB = (unsigned short*)(ws + 983040);    // 589824 f
    unsigned short* xb16   = (unsigned short*)(ws + 1572864);   // 417792 f
    float*          D      = ws + 1990656;                      // 295936 f
    unsigned int*   gmax   = (unsigned int*)(ws + 2286592);     // 3072
    unsigned short* rwb16  = (unsigned short*)(ws + 2289664);   // 12288 f

    int nb = 0;
    if (hipOccupancyMaxActiveBlocksPerMultiprocessor(
            &nb, (const void*)mega, 256, 0) != hipSuccess || nb < 1)
        nb = 4;
    if (nb > 6) nb = 6;
    int grid = nb * 256;                       // 256 CUs on MI355X

    void* args[] = {
        (void*)&h_re, (void*)&h_share, (void*)&r_w, (void*)&hid_w, (void*)&rel_w,
        (void*)&mask, (void*)&r_b, (void*)&hid_b, (void*)&ln_g, (void*)&ln_b,
        (void*)&rel_b, (void*)&apack, (void*)&wpackA, (void*)&wpackB,
        (void*)&rwb16, (void*)&xb16, (void*)&gmax, (void*)&D, (void*)&out
    };
    hipLaunchCooperativeKernel((const void*)mega, dim3(grid), dim3(256),
                               args, 0, stream);
}

// Round 11
// 77.120 us; speedup vs baseline: 4.3881x; 4.3881x over previous
//
#include <hip/hip_runtime.h>
#include <hip/hip_bf16.h>
#include <math.h>

#define L 128
#define B 4
#define H 768
#define LN_EPS 1e-5f
#define XROWS 272            // [p1:0..127 | p2:128..255 | pg:256 | ones:257 | 0:258..271]
#define DSTRIDE 73984        // 272*272

typedef __attribute__((ext_vector_type(8))) short short8;
typedef __attribute__((ext_vector_type(4))) float f32x4;
typedef __attribute__((ext_vector_type(16))) float f32x16;

static __device__ __forceinline__ unsigned f2bfu(float f) {
    unsigned u = __float_as_uint(f);
    return (u + 0x7FFFu + ((u >> 16) & 1u)) >> 16;
}
static __device__ __forceinline__ uint2 pk4(float4 v) {
    uint2 o;
    o.x = f2bfu(v.x) | (f2bfu(v.y) << 16);
    o.y = f2bfu(v.z) | (f2bfu(v.w) << 16);
    return o;
}
static __device__ __forceinline__ unsigned short f2b(float f) {
    union { __hip_bfloat16 h; unsigned short u; } cv;
    cv.h = __float2bfloat16(f);
    return cv.u;
}
static __device__ __forceinline__ float4 unpk4(uint2 p) {
    return make_float4(__uint_as_float(p.x << 16),
                       __uint_as_float(p.x & 0xffff0000u),
                       __uint_as_float(p.y << 16),
                       __uint_as_float(p.y & 0xffff0000u));
}
static __device__ __forceinline__ unsigned fkey(float x) {
    unsigned u = __float_as_uint(x);
    return (u >> 31) ? ~u : (u | 0x80000000u);
}

// ---------------------------------------------------------------------------
// kConv: all fp32->bf16 packing, coalesced READS + scattered 16B writes.
// ---------------------------------------------------------------------------
__global__ __launch_bounds__(256) void kConv(const float* __restrict__ h_re,
                                             const float* __restrict__ h_share,
                                             const float* __restrict__ r_w,
                                             const float* __restrict__ hid_w,
                                             const float* __restrict__ rel_w,
                                             unsigned short* __restrict__ apack,
                                             unsigned short* __restrict__ wpackA,
                                             unsigned short* __restrict__ wpackB,
                                             unsigned short* __restrict__ rwb2,
                                             unsigned short* __restrict__ xb16,
                                             unsigned int* __restrict__ gmax) {
    int t = blockIdx.x * 256 + threadIdx.x;
    if (t >= 402816) return;
    if (t < 98304) {                          // apack: Acat=[h_share|h_re]
        int m = t / 192, oct = t % 192, k = oct * 8;
        const float* src = (k < 768) ? (h_share + (size_t)m * 768 + k)
                                     : (h_re + (size_t)m * 768 + k - 768);
        float4 x = *(const float4*)src, y = *(const float4*)(src + 4);
        int mt = m >> 4, lr = m & 15, ks = k >> 5, lq = (k >> 3) & 3;
        uint2* dst = (uint2*)(apack + (((size_t)mt * 48 + ks) * 64 + lq * 16 + lr) * 8);
        dst[0] = pk4(x); dst[1] = pk4(y);
    } else if (t < 245760) {                  // wpackA: r_w rows
        int t2 = t - 98304;
        int n = t2 / 192, oct = t2 % 192, k = oct * 8;
        const float* src = r_w + (size_t)n * 1536 + k;
        float4 x = *(const float4*)src, y = *(const float4*)(src + 4);
        int nt = n >> 4, lr = n & 15, ks = k >> 5, lq = (k >> 3) & 3;
        uint2* dst = (uint2*)(wpackA + (((size_t)nt * 48 + ks) * 64 + lq * 16 + lr) * 8);
        dst[0] = pk4(x); dst[1] = pk4(y);
    } else if (t < 393216) {                  // wpackB: hid_w rows (w1|w2)
        int t3 = t - 245760;
        int n = t3 / 96, oct = t3 % 96, k = oct * 8;
        int half = (n >= 768) ? 1 : 0;
        const float* src = hid_w + (size_t)(n - half * 768) * 2304 + half * 768 + k;
        float4 x = *(const float4*)src, y = *(const float4*)(src + 4);
        int nt = n >> 4, lr = n & 15, ks = k >> 5, lq = (k >> 3) & 3;
        uint2* dst = (uint2*)(wpackB + (((size_t)nt * 24 + ks) * 64 + lq * 16 + lr) * 8);
        dst[0] = pk4(x); dst[1] = pk4(y);
    } else if (t < 396288) {                  // rwb2: B-frag-linear rel_w (32x32x16)
        int t4 = t - 393216;                  // 0..3071: (s, lane)
        int s = t4 >> 6, l = t4 & 63;
        int row = l & 31;
        uint2 o0 = make_uint2(0u, 0u), o1 = o0;
        if (row < 24) {
            const float* src = rel_w + (size_t)row * 768 + s * 16 + (l >> 5) * 8;
            o0 = pk4(*(const float4*)src);
            o1 = pk4(*(const float4*)(src + 4));
        }
        uint2* dst = (uint2*)(rwb2 + (size_t)t4 * 8);
        dst[0] = o0; dst[1] = o1;
    } else if (t < 402048) {                  // X tail rows 257..271
        int t5 = t - 396288;
        int b = t5 / 1440, rem = t5 % 1440, row = 257 + rem / 96, oct = rem % 96;
        unsigned val = (row == 257) ? 0x3F803F80u : 0u;
        uint2* dst = (uint2*)(xb16 + ((size_t)b * XROWS + row) * 768 + oct * 8);
        dst[0] = make_uint2(val, val); dst[1] = make_uint2(val, val);
    } else {                                  // gmax zero (768 x uint4)
        int t6 = t - 402048;
        ((uint4*)gmax)[t6] = make_uint4(0u, 0u, 0u, 0u);
    }
}

// ---------------------------------------------------------------------------
// kGemm: 1-wave blocks, 32x32 per wave, packed coalesced operands.
// ---------------------------------------------------------------------------
template<int KS>
static __device__ __forceinline__ void gemm_tile(const unsigned short* __restrict__ ap,
                                                 const unsigned short* __restrict__ wr,
                                                 f32x4 acc[2][2]) {
#pragma unroll 8
    for (int s = 0; s < KS; s++) {
        short8 a0 = *(const short8*)(ap + (size_t)s * 512);
        short8 a1 = *(const short8*)(ap + (size_t)(48 + s) * 512);
        short8 w0 = *(const short8*)(wr + (size_t)s * 512);
        short8 w1 = *(const short8*)(wr + (size_t)(KS + s) * 512);
        acc[0][0] = __builtin_amdgcn_mfma_f32_16x16x32_bf16(a0, w0, acc[0][0], 0, 0, 0);
        acc[0][1] = __builtin_amdgcn_mfma_f32_16x16x32_bf16(a0, w1, acc[0][1], 0, 0, 0);
        acc[1][0] = __builtin_amdgcn_mfma_f32_16x16x32_bf16(a1, w0, acc[1][0], 0, 0, 0);
        acc[1][1] = __builtin_amdgcn_mfma_f32_16x16x32_bf16(a1, w1, acc[1][1], 0, 0, 0);
    }
}

__global__ __launch_bounds__(64) void kGemm(const unsigned short* __restrict__ apack,
                                            const unsigned short* __restrict__ wpackA,
                                            const unsigned short* __restrict__ wpackB,
                                            unsigned int* __restrict__ gmax,
                                            unsigned short* __restrict__ xb16) {
    int id = blockIdx.x;
    int lane = threadIdx.x;
    int lq = lane >> 4, lr = lane & 15;
    f32x4 acc[2][2] = {{{0.f,0.f,0.f,0.f},{0.f,0.f,0.f,0.f}},
                       {{0.f,0.f,0.f,0.f},{0.f,0.f,0.f,0.f}}};
    if (id < 384) {
        int mt0 = (id / 24) * 2, nt0 = (id % 24) * 2;
        const unsigned short* ap = apack + (size_t)mt0 * 48 * 512 + lane * 8;
        const unsigned short* wr = wpackA + (size_t)nt0 * 48 * 512 + lane * 8;
        gemm_tile<48>(ap, wr, acc);
#pragma unroll
        for (int ni = 0; ni < 2; ni++)
#pragma unroll
            for (int q = 0; q < 4; q++) {
                float mx = fmaxf(acc[0][ni][q], acc[1][ni][q]);
                mx = fmaxf(mx, __shfl_xor(mx, 16, 64));
                mx = fmaxf(mx, __shfl_xor(mx, 32, 64));
                if (lq == 0) {
                    int n = (nt0 + ni) * 16 + lr;
                    atomicMax(&gmax[q * 768 + n], fkey(mx));
                }
            }
    } else {
        int id2 = id - 384;
        int mt0 = (id2 / 48) * 2, nt0 = (id2 % 48) * 2;
        const unsigned short* ap = apack + ((size_t)mt0 * 48 + 24) * 512 + lane * 8;
        const unsigned short* wr = wpackB + (size_t)nt0 * 24 * 512 + lane * 8;
        gemm_tile<24>(ap, wr, acc);
#pragma unroll
        for (int mi = 0; mi < 2; mi++)
#pragma unroll
            for (int ni = 0; ni < 2; ni++)
#pragma unroll
                for (int q = 0; q < 4; q++) {
                    int m = (mt0 + mi) * 16 + lq * 4 + q;
                    int n = (nt0 + ni) * 16 + lr;
                    int b = m & 3, l = m >> 2;
                    size_t row = (n < 768) ? (size_t)l : (size_t)(128 + l);
                    int col = (n < 768) ? n : n - 768;
                    xb16[((size_t)b * XROWS + row) * 768 + col] = f2b(acc[mi][ni][q]);
                }
    }
}

// ---------------------------------------------------------------------------
// kPg: decode gmax -> g = tanh(max+r_b), pg = g.w3 + hid_b -> X row 256 (bf16)
// ---------------------------------------------------------------------------
__global__ __launch_bounds__(256) void kPg(const unsigned int* __restrict__ gmax,
                                           const float* __restrict__ r_b,
                                           const float* __restrict__ hid_w,
                                           const float* __restrict__ hid_b,
                                           unsigned short* __restrict__ xb16) {
    __shared__ float sg[768];
    __shared__ float sp[4][64];
    int kt = blockIdx.x, b = blockIdx.y, tid = threadIdx.x;
    for (int v = tid; v < 768; v += 256) {
        unsigned key = gmax[b * 768 + v];
        unsigned bits = (key & 0x80000000u) ? (key & 0x7FFFFFFFu) : ~key;
        sg[v] = tanhf(__uint_as_float(bits) + r_b[v]);
    }
    __syncthreads();
    int kk = tid & 63, hc = tid >> 6;
    int k = kt * 64 + kk;
    const float4* w4 = (const float4*)hid_w;
    const float4* g4 = (const float4*)sg;
    float acc = 0.f;
    for (int h = hc * 48; h < hc * 48 + 48; h++) {
        float4 gv = g4[h];
        float4 wv = w4[(size_t)k * 576 + 384 + h];
        acc += gv.x * wv.x + gv.y * wv.y + gv.z * wv.z + gv.w * wv.w;
    }
    sp[hc][kk] = acc;
    __syncthreads();
    if (hc == 0) {
        float pgv = sp[0][kk] + sp[1][kk] + sp[2][kk] + sp[3][kk] + hid_b[k];
        xb16[((size_t)b * XROWS + 256) * 768 + k] = f2b(pgv);
    }
}

// ---------------------------------------------------------------------------
// kPack: permute-copy X (row-major bf16) -> xpack[b][17 t][24 ks][64 lane][8]
// (MFMA-fragment-linear). Coalesced 16B reads, scattered 16B writes.
// Same (row,k)->frag mapping as kGram's loads: row = 16t + (l&15),
// k = 32ks + (l>>4)*8 + e.
// ---------------------------------------------------------------------------
__global__ __launch_bounds__(256) void kPack(const unsigned short* __restrict__ xb16,
                                             unsigned short* __restrict__ xpack) {
    int t = blockIdx.x * 256 + threadIdx.x;      // 0..104447
    int b = t / 26112, rem = t % 26112;
    int r = rem / 96, k8 = rem % 96;             // r: 0..271, k8: 16B chunk index
    const uint2* src = (const uint2*)(xb16 + ((size_t)b * XROWS + r) * 768 + k8 * 8);
    uint2 v0 = src[0], v1 = src[1];
    size_t dst = ((((size_t)(b * 17 + (r >> 4)) * 24 + (k8 >> 2)) * 64)
                  + (k8 & 3) * 16 + (r & 15)) * 8;
    uint2* d = (uint2*)(xpack + dst);
    d[0] = v0; d[1] = v1;
}

// ---------------------------------------------------------------------------
// kGram: D[b] = X[b].X[b]^T via MFMA, operands from xpack (fully coalesced:
// each step's frag load = one contiguous 1KB wave transaction).
// ---------------------------------------------------------------------------
__global__ __launch_bounds__(64) void kGram(const unsigned short* __restrict__ xpack,
                                            float* __restrict__ D) {
    int it = blockIdx.x, jt = blockIdx.y, b = blockIdx.z;
    int lane = threadIdx.x, lq = lane >> 4, lr = lane & 15;
    const unsigned short* ar = xpack + ((size_t)(b * 17 + it) * 24 * 64 + lane) * 8;
    const unsigned short* wr = xpack + ((size_t)(b * 17 + jt) * 24 * 64 + lane) * 8;
    f32x4 acc = {0.f, 0.f, 0.f, 0.f};
#pragma unroll 8
    for (int s = 0; s < 24; s++) {
        short8 a = *(const short8*)(ar + (size_t)s * 512);
        short8 w = *(const short8*)(wr + (size_t)s * 512);
        acc = __builtin_amdgcn_mfma_f32_16x16x32_bf16(a, w, acc, 0, 0, 0);
    }
    float* Db = D + (size_t)b * DSTRIDE;
#pragma unroll
    for (int q = 0; q < 4; q++)
        Db[(size_t)(it * 16 + lq * 4 + q) * XROWS + jt * 16 + lr] = acc[q];
}

// ---------------------------------------------------------------------------
// kC: block (i, b, jg) -> 32 j's, 512 thr (8 waves).
// Phase1: LN+ELU (stats from D) -> zls bf16 [32][780].
// Phase2: one 32x32x16 MFMA chain per wave, K split 8 ways, coalesced B-frags,
//         f32 partial reduce in aliased LDS.
// ---------------------------------------------------------------------------
__global__ __launch_bounds__(512, 6) void kC(const unsigned short* __restrict__ xb16,
                                             const float* __restrict__ ln_g,
                                             const float* __restrict__ ln_b,
                                             const unsigned short* __restrict__ rwb2,
                                             const float* __restrict__ rel_b,
                                             const float* __restrict__ D,
                                             const float* __restrict__ mask,
                                             float* __restrict__ out) {
    __shared__ __align__(16) unsigned char smem[49920];   // 32*780*2
    __shared__ float smu[32], srs[32];
    unsigned short (*zls)[780] = (unsigned short (*)[780])smem;
    int i = blockIdx.x, b = blockIdx.y, j0 = blockIdx.z * 32;
    int tid = threadIdx.x, lane = tid & 63, wave = tid >> 6;

    if (tid < 32) {
        const float* Db = D + (size_t)b * DSTRIDE;
        int vr = 128 + j0 + tid;
        float Su1 = Db[(size_t)i * XROWS + 257];
        float Su2 = Db[(size_t)i * XROWS + i];
        float up  = Db[(size_t)i * XROWS + 256];
        float Sp1 = Db[(size_t)256 * XROWS + 257];
        float Sp2 = Db[(size_t)256 * XROWS + 256];
        float Sv1 = Db[(size_t)vr * XROWS + 257];
        float Sv2 = Db[(size_t)vr * XROWS + vr];
        float Dij = Db[(size_t)i * XROWS + vr];
        float cvj = Db[(size_t)vr * XROWS + 256];
        float s1 = Su1 + Sp1 + Sv1;
        float s2 = Su2 + Sp2 + Sv2 + 2.f * (Dij + up + cvj);
        float mu = s1 * (1.f / 768.f);
        smu[tid] = mu;
        srs[tid] = rsqrtf(s2 * (1.f / 768.f) - mu * mu + LN_EPS);
    }
    const uint2* ur = (const uint2*)(xb16 + ((size_t)b * XROWS + i) * 768);
    const uint2* pr = (const uint2*)(xb16 + ((size_t)b * XROWS + 256) * 768);
    const float4* lg4 = (const float4*)ln_g;
    const float4* lb4 = (const float4*)ln_b;
    float4 t1[3], gg[3], bb[3];
#pragma unroll
    for (int s = 0; s < 3; s++) {
        int c = lane + 64 * s;
        float4 x = unpk4(ur[c]), y = unpk4(pr[c]);
        t1[s] = make_float4(x.x + y.x, x.y + y.y, x.z + y.z, x.w + y.w);
        gg[s] = lg4[c];
        bb[s] = lb4[c];
    }
    __syncthreads();

#pragma unroll
    for (int jj = 0; jj < 4; jj++) {
        int j = wave * 4 + jj;
        float mu = smu[j], rs = srs[j];
        const uint2* vr2 = (const uint2*)(xb16 + ((size_t)b * XROWS + 128 + j0 + j) * 768);
        uint2* zrow = (uint2*)&zls[j][0];
#pragma unroll
        for (int s = 0; s < 3; s++) {
            int c = lane + 64 * s;
            float4 vv = unpk4(vr2[c]);
            float A0 = rs * gg[s].x, A1 = rs * gg[s].y, A2 = rs * gg[s].z, A3 = rs * gg[s].w;
            float C0 = fmaf(-mu, A0, bb[s].x), C1 = fmaf(-mu, A1, bb[s].y);
            float C2 = fmaf(-mu, A2, bb[s].z), C3 = fmaf(-mu, A3, bb[s].w);
            float z0 = fmaf(t1[s].x + vv.x, A0, C0);
            float z1 = fmaf(t1[s].y + vv.y, A1, C1);
            float z2 = fmaf(t1[s].z + vv.z, A2, C2);
            float z3 = fmaf(t1[s].w + vv.w, A3, C3);
            z0 = fmaxf(z0, __expf(fminf(z0, 0.f)) - 1.f);
            z1 = fmaxf(z1, __expf(fminf(z1, 0.f)) - 1.f);
            z2 = fmaxf(z2, __expf(fminf(z2, 0.f)) - 1.f);
            z3 = fmaxf(z3, __expf(fminf(z3, 0.f)) - 1.f);
            uint2 o;
            o.x = (unsigned)f2b(z0) | ((unsigned)f2b(z1) << 16);
            o.y = (unsigned)f2b(z2) | ((unsigned)f2b(z3) << 16);
            zrow[c] = o;
        }
    }
    __syncthreads();

    // phase 2: wave kq handles K-steps kq*6..kq*6+5 of 48 (K=768, 16 per step)
    int arow = lane & 31, ahi = lane >> 5;
    f32x16 acc = {0.f,0.f,0.f,0.f, 0.f,0.f,0.f,0.f, 0.f,0.f,0.f,0.f, 0.f,0.f,0.f,0.f};
    const unsigned short* bptr = rwb2 + ((size_t)(wave * 6) * 64 + lane) * 8;
#pragma unroll
    for (int st = 0; st < 6; st++) {
        int s = wave * 6 + st;
        short8 a  = *(const short8*)&zls[arow][s * 16 + ahi * 8];
        short8 bf = *(const short8*)(bptr + (size_t)st * 512);
        acc = __builtin_amdgcn_mfma_f32_32x32x16_bf16(a, bf, acc, 0, 0, 0);
    }
    __syncthreads();
    float* pf = (float*)smem;                 // 8 waves x 1024 f32 = 32 KB
#pragma unroll
    for (int r = 0; r < 16; r++) {
        int row = (r & 3) + 8 * (r >> 2) + 4 * ahi;
        pf[wave * 1024 + row * 32 + arow] = acc[r];
    }
    __syncthreads();

#pragma unroll
    for (int e0 = 0; e0 < 2; e0++) {
        int e = tid + e0 * 512;
        int row = e >> 5, col = e & 31;
        if (col < 24) {
            float v = 0.f;
#pragma unroll
            for (int w = 0; w < 8; w++) v += pf[w * 1024 + e];
            int jgl = j0 + row;
            float mval = mask[i * 4 + b] * mask[jgl * 4 + b];
            out[((size_t)(i * 128 + jgl) * 4 + b) * 24 + col] =
                mval / (1.f + __expf(-(v + rel_b[col])));
        }
    }
}

// ---------------------------------------------------------------------------
extern "C" void kernel_launch(void* const* d_in, const int* in_sizes, int n_in,
                              void* d_out, int out_size, void* d_ws, size_t ws_size,
                              hipStream_t stream) {
    const float* h_re    = (const float*)d_in[0];
    const float* h_share = (const float*)d_in[1];
    const float* mask    = (const float*)d_in[2];
    const float* r_w     = (const float*)d_in[3];
    const float* r_b     = (const float*)d_in[4];
    const float* hid_w   = (const float*)d_in[5];
    const float* hid_b   = (const float*)d_in[6];
    const float* ln_g    = (const float*)d_in[7];
    const float* ln_b    = (const float*)d_in[8];
    const float* rel_w   = (const float*)d_in[9];
    const float* rel_b   = (const float*)d_in[10];
    float* out = (float*)d_out;

    float* ws = (float*)d_ws;
    unsigned short* apack  = (unsigned short*)(ws);             // 393216 f
    unsigned short* wpackA = (unsigned short*)(ws + 393216);    // 589824 f
    unsigned short* wpackB = (unsigned short*)(ws + 983040);    // 589824 f
    unsigned short* xb16   = (unsigned short*)(ws + 1572864);   // 417792 f
    float*          D      = ws + 1990656;                      // 295936 f
    unsigned int*   gmax   = (unsigned int*)(ws + 2286592);     // 3072
    unsigned short* rwb2   = (unsigned short*)(ws + 2289664);   // 12288 f
    // xpack aliases apack (dead after kGemm): 835584 shorts = 417792 f
    unsigned short* xpack  = (unsigned short*)(ws);

    kConv<<<1574, 256, 0, stream>>>(h_re, h_share, r_w, hid_w, rel_w,
                                    apack, wpackA, wpackB, rwb2, xb16, gmax);
    kGemm<<<1152, 64, 0, stream>>>(apack, wpackA, wpackB, gmax, xb16);
    kPg<<<dim3(12, 4), 256, 0, stream>>>(gmax, r_b, hid_w, hid_b, xb16);
    kPack<<<408, 256, 0, stream>>>(xb16, xpack);
    kGram<<<dim3(17, 17, 4), 64, 0, stream>>>(xpack, D);
    kC<<<dim3(L, B, 4), 512, 0, stream>>>(xb16, ln_g, ln_b, rwb2, rel_b,
                                          D, mask, out);
}

// Round 12
// 73.461 us; speedup vs baseline: 4.6067x; 1.0498x over previous
//
#include <hip/hip_runtime.h>
#include <hip/hip_bf16.h>
#include <math.h>

#define L 128
#define B 4
#define H 768
#define LN_EPS 1e-5f
#define XROWS 272            // [p1:0..127 | p2:128..255 | pg:256 | ones:257 | 0:258..271]
#define DSTRIDE 73984        // 272*272

typedef __attribute__((ext_vector_type(8))) short short8;
typedef __attribute__((ext_vector_type(4))) float f32x4;
typedef __attribute__((ext_vector_type(16))) float f32x16;

static __device__ __forceinline__ unsigned f2bfu(float f) {
    unsigned u = __float_as_uint(f);
    return (u + 0x7FFFu + ((u >> 16) & 1u)) >> 16;
}
static __device__ __forceinline__ uint2 pk4(float4 v) {
    uint2 o;
    o.x = f2bfu(v.x) | (f2bfu(v.y) << 16);
    o.y = f2bfu(v.z) | (f2bfu(v.w) << 16);
    return o;
}
static __device__ __forceinline__ unsigned short f2b(float f) {
    union { __hip_bfloat16 h; unsigned short u; } cv;
    cv.h = __float2bfloat16(f);
    return cv.u;
}
static __device__ __forceinline__ float4 unpk4(uint2 p) {
    return make_float4(__uint_as_float(p.x << 16),
                       __uint_as_float(p.x & 0xffff0000u),
                       __uint_as_float(p.y << 16),
                       __uint_as_float(p.y & 0xffff0000u));
}
static __device__ __forceinline__ unsigned fkey(float x) {
    unsigned u = __float_as_uint(x);
    return (u >> 31) ? ~u : (u | 0x80000000u);
}

// ---------------------------------------------------------------------------
// kConv: all fp32->bf16 packing, coalesced READS + scattered 16B writes.
// (xb16 tail rows dropped: tile-16 fragments are generated in kPgPack now.)
// ---------------------------------------------------------------------------
__global__ __launch_bounds__(256) void kConv(const float* __restrict__ h_re,
                                             const float* __restrict__ h_share,
                                             const float* __restrict__ r_w,
                                             const float* __restrict__ hid_w,
                                             const float* __restrict__ rel_w,
                                             unsigned short* __restrict__ apack,
                                             unsigned short* __restrict__ wpackA,
                                             unsigned short* __restrict__ wpackB,
                                             unsigned short* __restrict__ rwb2,
                                             unsigned int* __restrict__ gmax) {
    int t = blockIdx.x * 256 + threadIdx.x;
    if (t >= 397056) return;
    if (t < 98304) {                          // apack: Acat=[h_share|h_re]
        int m = t / 192, oct = t % 192, k = oct * 8;
        const float* src = (k < 768) ? (h_share + (size_t)m * 768 + k)
                                     : (h_re + (size_t)m * 768 + k - 768);
        float4 x = *(const float4*)src, y = *(const float4*)(src + 4);
        int mt = m >> 4, lr = m & 15, ks = k >> 5, lq = (k >> 3) & 3;
        uint2* dst = (uint2*)(apack + (((size_t)mt * 48 + ks) * 64 + lq * 16 + lr) * 8);
        dst[0] = pk4(x); dst[1] = pk4(y);
    } else if (t < 245760) {                  // wpackA: r_w rows
        int t2 = t - 98304;
        int n = t2 / 192, oct = t2 % 192, k = oct * 8;
        const float* src = r_w + (size_t)n * 1536 + k;
        float4 x = *(const float4*)src, y = *(const float4*)(src + 4);
        int nt = n >> 4, lr = n & 15, ks = k >> 5, lq = (k >> 3) & 3;
        uint2* dst = (uint2*)(wpackA + (((size_t)nt * 48 + ks) * 64 + lq * 16 + lr) * 8);
        dst[0] = pk4(x); dst[1] = pk4(y);
    } else if (t < 393216) {                  // wpackB: hid_w rows (w1|w2)
        int t3 = t - 245760;
        int n = t3 / 96, oct = t3 % 96, k = oct * 8;
        int half = (n >= 768) ? 1 : 0;
        const float* src = hid_w + (size_t)(n - half * 768) * 2304 + half * 768 + k;
        float4 x = *(const float4*)src, y = *(const float4*)(src + 4);
        int nt = n >> 4, lr = n & 15, ks = k >> 5, lq = (k >> 3) & 3;
        uint2* dst = (uint2*)(wpackB + (((size_t)nt * 24 + ks) * 64 + lq * 16 + lr) * 8);
        dst[0] = pk4(x); dst[1] = pk4(y);
    } else if (t < 396288) {                  // rwb2: B-frag-linear rel_w (32x32x16)
        int t4 = t - 393216;                  // 0..3071: (s, lane)
        int s = t4 >> 6, l = t4 & 63;
        int row = l & 31;
        uint2 o0 = make_uint2(0u, 0u), o1 = o0;
        if (row < 24) {
            const float* src = rel_w + (size_t)row * 768 + s * 16 + (l >> 5) * 8;
            o0 = pk4(*(const float4*)src);
            o1 = pk4(*(const float4*)(src + 4));
        }
        uint2* dst = (uint2*)(rwb2 + (size_t)t4 * 8);
        dst[0] = o0; dst[1] = o1;
    } else {                                  // gmax zero (768 scalars)
        int t6 = t - 396288;
        gmax[t6] = 0u;
        gmax[768 + t6] = 0u;
        gmax[1536 + t6] = 0u;
        gmax[2304 + t6] = 0u;
    }
}

// ---------------------------------------------------------------------------
// kGemm: 1-wave blocks, 32x32 per wave, packed coalesced operands.
// ---------------------------------------------------------------------------
template<int KS>
static __device__ __forceinline__ void gemm_tile(const unsigned short* __restrict__ ap,
                                                 const unsigned short* __restrict__ wr,
                                                 f32x4 acc[2][2]) {
#pragma unroll 8
    for (int s = 0; s < KS; s++) {
        short8 a0 = *(const short8*)(ap + (size_t)s * 512);
        short8 a1 = *(const short8*)(ap + (size_t)(48 + s) * 512);
        short8 w0 = *(const short8*)(wr + (size_t)s * 512);
        short8 w1 = *(const short8*)(wr + (size_t)(KS + s) * 512);
        acc[0][0] = __builtin_amdgcn_mfma_f32_16x16x32_bf16(a0, w0, acc[0][0], 0, 0, 0);
        acc[0][1] = __builtin_amdgcn_mfma_f32_16x16x32_bf16(a0, w1, acc[0][1], 0, 0, 0);
        acc[1][0] = __builtin_amdgcn_mfma_f32_16x16x32_bf16(a1, w0, acc[1][0], 0, 0, 0);
        acc[1][1] = __builtin_amdgcn_mfma_f32_16x16x32_bf16(a1, w1, acc[1][1], 0, 0, 0);
    }
}

__global__ __launch_bounds__(64) void kGemm(const unsigned short* __restrict__ apack,
                                            const unsigned short* __restrict__ wpackA,
                                            const unsigned short* __restrict__ wpackB,
                                            unsigned int* __restrict__ gmax,
                                            unsigned short* __restrict__ xb16) {
    int id = blockIdx.x;
    int lane = threadIdx.x;
    int lq = lane >> 4, lr = lane & 15;
    f32x4 acc[2][2] = {{{0.f,0.f,0.f,0.f},{0.f,0.f,0.f,0.f}},
                       {{0.f,0.f,0.f,0.f},{0.f,0.f,0.f,0.f}}};
    if (id < 384) {
        int mt0 = (id / 24) * 2, nt0 = (id % 24) * 2;
        const unsigned short* ap = apack + (size_t)mt0 * 48 * 512 + lane * 8;
        const unsigned short* wr = wpackA + (size_t)nt0 * 48 * 512 + lane * 8;
        gemm_tile<48>(ap, wr, acc);
#pragma unroll
        for (int ni = 0; ni < 2; ni++)
#pragma unroll
            for (int q = 0; q < 4; q++) {
                float mx = fmaxf(acc[0][ni][q], acc[1][ni][q]);
                mx = fmaxf(mx, __shfl_xor(mx, 16, 64));
                mx = fmaxf(mx, __shfl_xor(mx, 32, 64));
                if (lq == 0) {
                    int n = (nt0 + ni) * 16 + lr;
                    atomicMax(&gmax[q * 768 + n], fkey(mx));
                }
            }
    } else {
        int id2 = id - 384;
        int mt0 = (id2 / 48) * 2, nt0 = (id2 % 48) * 2;
        const unsigned short* ap = apack + ((size_t)mt0 * 48 + 24) * 512 + lane * 8;
        const unsigned short* wr = wpackB + (size_t)nt0 * 24 * 512 + lane * 8;
        gemm_tile<24>(ap, wr, acc);
#pragma unroll
        for (int mi = 0; mi < 2; mi++)
#pragma unroll
            for (int ni = 0; ni < 2; ni++)
#pragma unroll
                for (int q = 0; q < 4; q++) {
                    int m = (mt0 + mi) * 16 + lq * 4 + q;
                    int n = (nt0 + ni) * 16 + lr;
                    int b = m & 3, l = m >> 2;
                    size_t row = (n < 768) ? (size_t)l : (size_t)(128 + l);
                    int col = (n < 768) ? n : n - 768;
                    xb16[((size_t)b * XROWS + row) * 768 + col] = f2b(acc[mi][ni][q]);
                }
    }
}

// ---------------------------------------------------------------------------
// kPgPack (fused kPg + kPack):
//  blocks 0..47   : decode gmax -> g=tanh(max+r_b); pg = g.w3 + hid_b;
//                   write xb16 row 256 (bf16) AND xpack tile 16 fragments for
//                   its own 2 ks chunks (row 256 = pg, 257 = ones, rest = 0).
//  blocks 48..431 : permute-copy X rows 0..255 (p1/p2) -> xpack tiles 0..15.
// ---------------------------------------------------------------------------
__global__ __launch_bounds__(256) void kPgPack(const unsigned int* __restrict__ gmax,
                                               const float* __restrict__ r_b,
                                               const float* __restrict__ hid_w,
                                               const float* __restrict__ hid_b,
                                               unsigned short* xb16,
                                               unsigned short* __restrict__ xpack) {
    int blk = blockIdx.x, tid = threadIdx.x;
    if (blk >= 48) {
        int t = (blk - 48) * 256 + tid;            // 0..98303
        int b = t / 24576, rem = t % 24576;
        int r = rem / 96, k8 = rem % 96;
        const uint2* src = (const uint2*)(xb16 + ((size_t)b * XROWS + r) * 768 + k8 * 8);
        uint2 v0 = src[0], v1 = src[1];
        size_t dst = ((((size_t)(b * 17 + (r >> 4)) * 24 + (k8 >> 2)) * 64)
                      + (k8 & 3) * 16 + (r & 15)) * 8;
        uint2* d = (uint2*)(xpack + dst);
        d[0] = v0; d[1] = v1;
        return;
    }
    __shared__ float sg[768];
    __shared__ float sp[4][64];
    __shared__ float spg[64];
    int kt = blk % 12, b = blk / 12;
    for (int v = tid; v < 768; v += 256) {
        unsigned key = gmax[b * 768 + v];
        unsigned bits = (key & 0x80000000u) ? (key & 0x7FFFFFFFu) : ~key;
        sg[v] = tanhf(__uint_as_float(bits) + r_b[v]);
    }
    __syncthreads();
    int kk = tid & 63, hc = tid >> 6;
    int k = kt * 64 + kk;
    const float4* w4 = (const float4*)hid_w;
    const float4* g4 = (const float4*)sg;
    float acc = 0.f;
    for (int h = hc * 48; h < hc * 48 + 48; h++) {
        float4 gv = g4[h];
        float4 wv = w4[(size_t)k * 576 + 384 + h];
        acc += gv.x * wv.x + gv.y * wv.y + gv.z * wv.z + gv.w * wv.w;
    }
    sp[hc][kk] = acc;
    __syncthreads();
    if (hc == 0) {
        float pgv = sp[0][kk] + sp[1][kk] + sp[2][kk] + sp[3][kk] + hid_b[k];
        spg[kk] = pgv;
        xb16[((size_t)b * XROWS + 256) * 768 + k] = f2b(pgv);
    }
    __syncthreads();
    // pack tile 16 fragments for ks = 2kt, 2kt+1
    if (tid < 128) {
        int ksl = tid >> 6, lane = tid & 63;
        int ks = kt * 2 + ksl;
        int row16 = lane & 15;
        int kbase = ksl * 32 + (lane >> 4) * 8;   // local pg index base (0..63)
        unsigned short vals[8];
        if (row16 == 0) {
#pragma unroll
            for (int e = 0; e < 8; e++) vals[e] = f2b(spg[kbase + e]);
        } else if (row16 == 1) {
#pragma unroll
            for (int e = 0; e < 8; e++) vals[e] = 0x3F80;   // 1.0 bf16
        } else {
#pragma unroll
            for (int e = 0; e < 8; e++) vals[e] = 0;
        }
        uint2* d = (uint2*)(xpack + (((size_t)(b * 17 + 16) * 24 + ks) * 64 + lane) * 8);
        d[0] = *(uint2*)&vals[0];
        d[1] = *(uint2*)&vals[4];
    }
}

// ---------------------------------------------------------------------------
// kGram: only the ~97 tiles kC consumes: cross (it 0..7, jt 8..15), diagonal
// (0..15), and the pg/ones column (it 0..16, jt 16). grid (97, 4).
// ---------------------------------------------------------------------------
__global__ __launch_bounds__(64) void kGram(const unsigned short* __restrict__ xpack,
                                            float* __restrict__ D) {
    int t = blockIdx.x, b = blockIdx.y;
    int it, jt;
    if (t < 64)      { it = t >> 3;  jt = 8 + (t & 7); }
    else if (t < 80) { it = t - 64;  jt = t - 64; }
    else             { it = t - 80;  jt = 16; }
    int lane = threadIdx.x, lq = lane >> 4, lr = lane & 15;
    const unsigned short* ar = xpack + ((size_t)(b * 17 + it) * 24 * 64 + lane) * 8;
    const unsigned short* wr = xpack + ((size_t)(b * 17 + jt) * 24 * 64 + lane) * 8;
    f32x4 acc = {0.f, 0.f, 0.f, 0.f};
#pragma unroll 8
    for (int s = 0; s < 24; s++) {
        short8 a = *(const short8*)(ar + (size_t)s * 512);
        short8 w = *(const short8*)(wr + (size_t)s * 512);
        acc = __builtin_amdgcn_mfma_f32_16x16x32_bf16(a, w, acc, 0, 0, 0);
    }
    float* Db = D + (size_t)b * DSTRIDE;
#pragma unroll
    for (int q = 0; q < 4; q++)
        Db[(size_t)(it * 16 + lq * 4 + q) * XROWS + jt * 16 + lr] = acc[q];
}

// ---------------------------------------------------------------------------
// kC: block (i, b, jg) -> 32 j's, 512 thr (8 waves).
// Phase1: LN+ELU (stats from D) -> zls bf16 [32][780].
// Phase2: one 32x32x16 MFMA chain per wave, K split 8 ways, coalesced B-frags,
//         f32 partial reduce in aliased LDS.
// ---------------------------------------------------------------------------
__global__ __launch_bounds__(512, 6) void kC(const unsigned short* __restrict__ xb16,
                                             const float* __restrict__ ln_g,
                                             const float* __restrict__ ln_b,
                                             const unsigned short* __restrict__ rwb2,
                                             const float* __restrict__ rel_b,
                                             const float* __restrict__ D,
                                             const float* __restrict__ mask,
                                             float* __restrict__ out) {
    __shared__ __align__(16) unsigned char smem[49920];   // 32*780*2
    __shared__ float smu[32], srs[32];
    unsigned short (*zls)[780] = (unsigned short (*)[780])smem;
    int i = blockIdx.x, b = blockIdx.y, j0 = blockIdx.z * 32;
    int tid = threadIdx.x, lane = tid & 63, wave = tid >> 6;

    if (tid < 32) {
        const float* Db = D + (size_t)b * DSTRIDE;
        int vr = 128 + j0 + tid;
        float Su1 = Db[(size_t)i * XROWS + 257];
        float Su2 = Db[(size_t)i * XROWS + i];
        float up  = Db[(size_t)i * XROWS + 256];
        float Sp1 = Db[(size_t)256 * XROWS + 257];
        float Sp2 = Db[(size_t)256 * XROWS + 256];
        float Sv1 = Db[(size_t)vr * XROWS + 257];
        float Sv2 = Db[(size_t)vr * XROWS + vr];
        float Dij = Db[(size_t)i * XROWS + vr];
        float cvj = Db[(size_t)vr * XROWS + 256];
        float s1 = Su1 + Sp1 + Sv1;
        float s2 = Su2 + Sp2 + Sv2 + 2.f * (Dij + up + cvj);
        float mu = s1 * (1.f / 768.f);
        smu[tid] = mu;
        srs[tid] = rsqrtf(s2 * (1.f / 768.f) - mu * mu + LN_EPS);
    }
    const uint2* ur = (const uint2*)(xb16 + ((size_t)b * XROWS + i) * 768);
    const uint2* pr = (const uint2*)(xb16 + ((size_t)b * XROWS + 256) * 768);
    const float4* lg4 = (const float4*)ln_g;
    const float4* lb4 = (const float4*)ln_b;
    float4 t1[3], gg[3], bb[3];
#pragma unroll
    for (int s = 0; s < 3; s++) {
        int c = lane + 64 * s;
        float4 x = unpk4(ur[c]), y = unpk4(pr[c]);
        t1[s] = make_float4(x.x + y.x, x.y + y.y, x.z + y.z, x.w + y.w);
        gg[s] = lg4[c];
        bb[s] = lb4[c];
    }
    __syncthreads();

#pragma unroll
    for (int jj = 0; jj < 4; jj++) {
        int j = wave * 4 + jj;
        float mu = smu[j], rs = srs[j];
        const uint2* vr2 = (const uint2*)(xb16 + ((size_t)b * XROWS + 128 + j0 + j) * 768);
        uint2* zrow = (uint2*)&zls[j][0];
#pragma unroll
        for (int s = 0; s < 3; s++) {
            int c = lane + 64 * s;
            float4 vv = unpk4(vr2[c]);
            float A0 = rs * gg[s].x, A1 = rs * gg[s].y, A2 = rs * gg[s].z, A3 = rs * gg[s].w;
            float C0 = fmaf(-mu, A0, bb[s].x), C1 = fmaf(-mu, A1, bb[s].y);
            float C2 = fmaf(-mu, A2, bb[s].z), C3 = fmaf(-mu, A3, bb[s].w);
            float z0 = fmaf(t1[s].x + vv.x, A0, C0);
            float z1 = fmaf(t1[s].y + vv.y, A1, C1);
            float z2 = fmaf(t1[s].z + vv.z, A2, C2);
            float z3 = fmaf(t1[s].w + vv.w, A3, C3);
            z0 = fmaxf(z0, __expf(fminf(z0, 0.f)) - 1.f);
            z1 = fmaxf(z1, __expf(fminf(z1, 0.f)) - 1.f);
            z2 = fmaxf(z2, __expf(fminf(z2, 0.f)) - 1.f);
            z3 = fmaxf(z3, __expf(fminf(z3, 0.f)) - 1.f);
            uint2 o;
            o.x = (unsigned)f2b(z0) | ((unsigned)f2b(z1) << 16);
            o.y = (unsigned)f2b(z2) | ((unsigned)f2b(z3) << 16);
            zrow[c] = o;
        }
    }
    __syncthreads();

    // phase 2: wave kq handles K-steps kq*6..kq*6+5 of 48 (K=768, 16 per step)
    int arow = lane & 31, ahi = lane >> 5;
    f32x16 acc = {0.f,0.f,0.f,0.f, 0.f,0.f,0.f,0.f, 0.f,0.f,0.f,0.f, 0.f,0.f,0.f,0.f};
    const unsigned short* bptr = rwb2 + ((size_t)(wave * 6) * 64 + lane) * 8;
#pragma unroll
    for (int st = 0; st < 6; st++) {
        int s = wave * 6 + st;
        short8 a  = *(const short8*)&zls[arow][s * 16 + ahi * 8];
        short8 bf = *(const short8*)(bptr + (size_t)st * 512);
        acc = __builtin_amdgcn_mfma_f32_32x32x16_bf16(a, bf, acc, 0, 0, 0);
    }
    __syncthreads();
    float* pf = (float*)smem;                 // 8 waves x 1024 f32 = 32 KB
#pragma unroll
    for (int r = 0; r < 16; r++) {
        int row = (r & 3) + 8 * (r >> 2) + 4 * ahi;
        pf[wave * 1024 + row * 32 + arow] = acc[r];
    }
    __syncthreads();

#pragma unroll
    for (int e0 = 0; e0 < 2; e0++) {
        int e = tid + e0 * 512;
        int row = e >> 5, col = e & 31;
        if (col < 24) {
            float v = 0.f;
#pragma unroll
            for (int w = 0; w < 8; w++) v += pf[w * 1024 + e];
            int jgl = j0 + row;
            float mval = mask[i * 4 + b] * mask[jgl * 4 + b];
            out[((size_t)(i * 128 + jgl) * 4 + b) * 24 + col] =
                mval / (1.f + __expf(-(v + rel_b[col])));
        }
    }
}

// ---------------------------------------------------------------------------
extern "C" void kernel_launch(void* const* d_in, const int* in_sizes, int n_in,
                              void* d_out, int out_size, void* d_ws, size_t ws_size,
                              hipStream_t stream) {
    const float* h_re    = (const float*)d_in[0];
    const float* h_share = (const float*)d_in[1];
    const float* mask    = (const float*)d_in[2];
    const float* r_w     = (const float*)d_in[3];
    const float* r_b     = (const float*)d_in[4];
    const float* hid_w   = (const float*)d_in[5];
    const float* hid_b   = (const float*)d_in[6];
    const float* ln_g    = (const float*)d_in[7];
    const float* ln_b    = (const float*)d_in[8];
    const float* rel_w   = (const float*)d_in[9];
    const float* rel_b   = (const float*)d_in[10];
    float* out = (float*)d_out;

    float* ws = (float*)d_ws;
    unsigned short* apack  = (unsigned short*)(ws);             // 393216 f
    unsigned short* wpackA = (unsigned short*)(ws + 393216);    // 589824 f
    unsigned short* wpackB = (unsigned short*)(ws + 983040);    // 589824 f
    unsigned short* xb16   = (unsigned short*)(ws + 1572864);   // 417792 f
    float*          D      = ws + 1990656;                      // 295936 f
    unsigned int*   gmax   = (unsigned int*)(ws + 2286592);     // 3072
    unsigned short* rwb2   = (unsigned short*)(ws + 2289664);   // 12288 f
    // xpack aliases apack (dead after kGemm): 835584 shorts = 417792 f
    unsigned short* xpack  = (unsigned short*)(ws);

    kConv<<<1552, 256, 0, stream>>>(h_re, h_share, r_w, hid_w, rel_w,
                                    apack, wpackA, wpackB, rwb2, gmax);
    kGemm<<<1152, 64, 0, stream>>>(apack, wpackA, wpackB, gmax, xb16);
    kPgPack<<<432, 256, 0, stream>>>(gmax, r_b, hid_w, hid_b, xb16, xpack);
    kGram<<<dim3(97, 4), 64, 0, stream>>>(xpack, D);
    kC<<<dim3(L, B, 4), 512, 0, stream>>>(xb16, ln_g, ln_b, rwb2, rel_b,
                                          D, mask, out);
}

// Round 13
// 65.888 us; speedup vs baseline: 5.1362x; 1.1149x over previous
//
#include <hip/hip_runtime.h>
#include <hip/hip_bf16.h>
#include <math.h>

#define L 128
#define B 4
#define H 768
#define LN_EPS 1e-5f
#define XROWS 272            // [p1:0..127 | p2:128..255 | pg:256 | ones:257 | 0:258..271]
#define DSTRIDE 73984        // 272*272

typedef __attribute__((ext_vector_type(8))) short short8;
typedef __attribute__((ext_vector_type(4))) float f32x4;
typedef __attribute__((ext_vector_type(16))) float f32x16;

static __device__ __forceinline__ unsigned f2bfu(float f) {
    unsigned u = __float_as_uint(f);
    return (u + 0x7FFFu + ((u >> 16) & 1u)) >> 16;
}
static __device__ __forceinline__ uint2 pk4(float4 v) {
    uint2 o;
    o.x = f2bfu(v.x) | (f2bfu(v.y) << 16);
    o.y = f2bfu(v.z) | (f2bfu(v.w) << 16);
    return o;
}
static __device__ __forceinline__ unsigned short f2b(float f) {
    union { __hip_bfloat16 h; unsigned short u; } cv;
    cv.h = __float2bfloat16(f);
    return cv.u;
}
static __device__ __forceinline__ float4 unpk4(uint2 p) {
    return make_float4(__uint_as_float(p.x << 16),
                       __uint_as_float(p.x & 0xffff0000u),
                       __uint_as_float(p.y << 16),
                       __uint_as_float(p.y & 0xffff0000u));
}
static __device__ __forceinline__ unsigned fkey(float x) {
    unsigned u = __float_as_uint(x);
    return (u >> 31) ? ~u : (u | 0x80000000u);
}

// ---------------------------------------------------------------------------
// kConv: all fp32->bf16 packing, coalesced READS + scattered 16B writes.
// ---------------------------------------------------------------------------
__global__ __launch_bounds__(256) void kConv(const float* __restrict__ h_re,
                                             const float* __restrict__ h_share,
                                             const float* __restrict__ r_w,
                                             const float* __restrict__ hid_w,
                                             const float* __restrict__ rel_w,
                                             unsigned short* __restrict__ apack,
                                             unsigned short* __restrict__ wpackA,
                                             unsigned short* __restrict__ wpackB,
                                             unsigned short* __restrict__ rwb2,
                                             unsigned int* __restrict__ gmax) {
    int t = blockIdx.x * 256 + threadIdx.x;
    if (t >= 397056) return;
    if (t < 98304) {                          // apack: Acat=[h_share|h_re]
        int m = t / 192, oct = t % 192, k = oct * 8;
        const float* src = (k < 768) ? (h_share + (size_t)m * 768 + k)
                                     : (h_re + (size_t)m * 768 + k - 768);
        float4 x = *(const float4*)src, y = *(const float4*)(src + 4);
        int mt = m >> 4, lr = m & 15, ks = k >> 5, lq = (k >> 3) & 3;
        uint2* dst = (uint2*)(apack + (((size_t)mt * 48 + ks) * 64 + lq * 16 + lr) * 8);
        dst[0] = pk4(x); dst[1] = pk4(y);
    } else if (t < 245760) {                  // wpackA: r_w rows
        int t2 = t - 98304;
        int n = t2 / 192, oct = t2 % 192, k = oct * 8;
        const float* src = r_w + (size_t)n * 1536 + k;
        float4 x = *(const float4*)src, y = *(const float4*)(src + 4);
        int nt = n >> 4, lr = n & 15, ks = k >> 5, lq = (k >> 3) & 3;
        uint2* dst = (uint2*)(wpackA + (((size_t)nt * 48 + ks) * 64 + lq * 16 + lr) * 8);
        dst[0] = pk4(x); dst[1] = pk4(y);
    } else if (t < 393216) {                  // wpackB: hid_w rows (w1|w2)
        int t3 = t - 245760;
        int n = t3 / 96, oct = t3 % 96, k = oct * 8;
        int half = (n >= 768) ? 1 : 0;
        const float* src = hid_w + (size_t)(n - half * 768) * 2304 + half * 768 + k;
        float4 x = *(const float4*)src, y = *(const float4*)(src + 4);
        int nt = n >> 4, lr = n & 15, ks = k >> 5, lq = (k >> 3) & 3;
        uint2* dst = (uint2*)(wpackB + (((size_t)nt * 24 + ks) * 64 + lq * 16 + lr) * 8);
        dst[0] = pk4(x); dst[1] = pk4(y);
    } else if (t < 396288) {                  // rwb2: B-frag-linear rel_w (32x32x16)
        int t4 = t - 393216;                  // 0..3071: (s, lane)
        int s = t4 >> 6, l = t4 & 63;
        int row = l & 31;
        uint2 o0 = make_uint2(0u, 0u), o1 = o0;
        if (row < 24) {
            const float* src = rel_w + (size_t)row * 768 + s * 16 + (l >> 5) * 8;
            o0 = pk4(*(const float4*)src);
            o1 = pk4(*(const float4*)(src + 4));
        }
        uint2* dst = (uint2*)(rwb2 + (size_t)t4 * 8);
        dst[0] = o0; dst[1] = o1;
    } else {                                  // gmax zero (768 scalars)
        int t6 = t - 396288;
        gmax[t6] = 0u;
        gmax[768 + t6] = 0u;
        gmax[1536 + t6] = 0u;
        gmax[2304 + t6] = 0u;
    }
}

// ---------------------------------------------------------------------------
// kGemm v2: 4-wave blocks, one 32x32 tile per block, K split 4 ways across
// waves (A: 12 steps/wave of 48; B: 6 of 24), LDS reduce, epilogue on wave 0.
// 1152 blocks x 256 thr -> 18 waves/CU (vs r12's 4.5): latency now hidden.
// ---------------------------------------------------------------------------
template<int KSW>
static __device__ __forceinline__ void gemm_steps(const unsigned short* __restrict__ a0p,
                                                  const unsigned short* __restrict__ a1p,
                                                  const unsigned short* __restrict__ w0p,
                                                  const unsigned short* __restrict__ w1p,
                                                  f32x4 acc[2][2]) {
#pragma unroll
    for (int s = 0; s < KSW; s++) {
        short8 a0 = *(const short8*)(a0p + (size_t)s * 512);
        short8 a1 = *(const short8*)(a1p + (size_t)s * 512);
        short8 w0 = *(const short8*)(w0p + (size_t)s * 512);
        short8 w1 = *(const short8*)(w1p + (size_t)s * 512);
        acc[0][0] = __builtin_amdgcn_mfma_f32_16x16x32_bf16(a0, w0, acc[0][0], 0, 0, 0);
        acc[0][1] = __builtin_amdgcn_mfma_f32_16x16x32_bf16(a0, w1, acc[0][1], 0, 0, 0);
        acc[1][0] = __builtin_amdgcn_mfma_f32_16x16x32_bf16(a1, w0, acc[1][0], 0, 0, 0);
        acc[1][1] = __builtin_amdgcn_mfma_f32_16x16x32_bf16(a1, w1, acc[1][1], 0, 0, 0);
    }
}

__global__ __launch_bounds__(256) void kGemm(const unsigned short* __restrict__ apack,
                                             const unsigned short* __restrict__ wpackA,
                                             const unsigned short* __restrict__ wpackB,
                                             unsigned int* __restrict__ gmax,
                                             unsigned short* __restrict__ xb16) {
    __shared__ float red[4][4][64][4];        // [wave][mi*2+ni][lane][q] = 16 KB
    int id = blockIdx.x;
    int tid = threadIdx.x, lane = tid & 63, wv = tid >> 6;
    int lq = lane >> 4, lr = lane & 15;
    bool isA = id < 384;
    f32x4 acc[2][2] = {{{0.f,0.f,0.f,0.f},{0.f,0.f,0.f,0.f}},
                       {{0.f,0.f,0.f,0.f},{0.f,0.f,0.f,0.f}}};
    int mt0, nt0;
    if (isA) {
        mt0 = (id / 24) * 2; nt0 = (id % 24) * 2;
        const unsigned short* a0p = apack + ((size_t)mt0 * 48 + wv * 12) * 512 + lane * 8;
        const unsigned short* w0p = wpackA + ((size_t)nt0 * 48 + wv * 12) * 512 + lane * 8;
        gemm_steps<12>(a0p, a0p + 48 * 512, w0p, w0p + 48 * 512, acc);
    } else {
        int id2 = id - 384;
        mt0 = (id2 / 48) * 2; nt0 = (id2 % 48) * 2;
        const unsigned short* a0p = apack + ((size_t)mt0 * 48 + 24 + wv * 6) * 512 + lane * 8;
        const unsigned short* w0p = wpackB + ((size_t)nt0 * 24 + wv * 6) * 512 + lane * 8;
        gemm_steps<6>(a0p, a0p + 48 * 512, w0p, w0p + 24 * 512, acc);
    }
#pragma unroll
    for (int mi = 0; mi < 2; mi++)
#pragma unroll
        for (int ni = 0; ni < 2; ni++)
            *(f32x4*)&red[wv][mi * 2 + ni][lane][0] = acc[mi][ni];
    __syncthreads();
    if (wv != 0) return;

    f32x4 s2[2][2];
#pragma unroll
    for (int mi = 0; mi < 2; mi++)
#pragma unroll
        for (int ni = 0; ni < 2; ni++) {
            f32x4 v = *(f32x4*)&red[0][mi * 2 + ni][lane][0];
#pragma unroll
            for (int w = 1; w < 4; w++) {
                f32x4 u = *(f32x4*)&red[w][mi * 2 + ni][lane][0];
                v[0] += u[0]; v[1] += u[1]; v[2] += u[2]; v[3] += u[3];
            }
            s2[mi][ni] = v;
        }

    if (isA) {
#pragma unroll
        for (int ni = 0; ni < 2; ni++)
#pragma unroll
            for (int q = 0; q < 4; q++) {
                float mx = fmaxf(s2[0][ni][q], s2[1][ni][q]);
                mx = fmaxf(mx, __shfl_xor(mx, 16, 64));
                mx = fmaxf(mx, __shfl_xor(mx, 32, 64));
                if (lq == 0) {
                    int n = (nt0 + ni) * 16 + lr;
                    atomicMax(&gmax[q * 768 + n], fkey(mx));
                }
            }
    } else {
#pragma unroll
        for (int mi = 0; mi < 2; mi++)
#pragma unroll
            for (int ni = 0; ni < 2; ni++)
#pragma unroll
                for (int q = 0; q < 4; q++) {
                    int m = (mt0 + mi) * 16 + lq * 4 + q;
                    int n = (nt0 + ni) * 16 + lr;
                    int b = m & 3, l = m >> 2;
                    size_t row = (n < 768) ? (size_t)l : (size_t)(128 + l);
                    int col = (n < 768) ? n : n - 768;
                    xb16[((size_t)b * XROWS + row) * 768 + col] = f2b(s2[mi][ni][q]);
                }
    }
}

// ---------------------------------------------------------------------------
// kPgPack (fused kPg + kPack): unchanged from r12.
// ---------------------------------------------------------------------------
__global__ __launch_bounds__(256) void kPgPack(const unsigned int* __restrict__ gmax,
                                               const float* __restrict__ r_b,
                                               const float* __restrict__ hid_w,
                                               const float* __restrict__ hid_b,
                                               unsigned short* xb16,
                                               unsigned short* __restrict__ xpack) {
    int blk = blockIdx.x, tid = threadIdx.x;
    if (blk >= 48) {
        int t = (blk - 48) * 256 + tid;            // 0..98303
        int b = t / 24576, rem = t % 24576;
        int r = rem / 96, k8 = rem % 96;
        const uint2* src = (const uint2*)(xb16 + ((size_t)b * XROWS + r) * 768 + k8 * 8);
        uint2 v0 = src[0], v1 = src[1];
        size_t dst = ((((size_t)(b * 17 + (r >> 4)) * 24 + (k8 >> 2)) * 64)
                      + (k8 & 3) * 16 + (r & 15)) * 8;
        uint2* d = (uint2*)(xpack + dst);
        d[0] = v0; d[1] = v1;
        return;
    }
    __shared__ float sg[768];
    __shared__ float sp[4][64];
    __shared__ float spg[64];
    int kt = blk % 12, b = blk / 12;
    for (int v = tid; v < 768; v += 256) {
        unsigned key = gmax[b * 768 + v];
        unsigned bits = (key & 0x80000000u) ? (key & 0x7FFFFFFFu) : ~key;
        sg[v] = tanhf(__uint_as_float(bits) + r_b[v]);
    }
    __syncthreads();
    int kk = tid & 63, hc = tid >> 6;
    int k = kt * 64 + kk;
    const float4* w4 = (const float4*)hid_w;
    const float4* g4 = (const float4*)sg;
    float acc = 0.f;
    for (int h = hc * 48; h < hc * 48 + 48; h++) {
        float4 gv = g4[h];
        float4 wv = w4[(size_t)k * 576 + 384 + h];
        acc += gv.x * wv.x + gv.y * wv.y + gv.z * wv.z + gv.w * wv.w;
    }
    sp[hc][kk] = acc;
    __syncthreads();
    if (hc == 0) {
        float pgv = sp[0][kk] + sp[1][kk] + sp[2][kk] + sp[3][kk] + hid_b[k];
        spg[kk] = pgv;
        xb16[((size_t)b * XROWS + 256) * 768 + k] = f2b(pgv);
    }
    __syncthreads();
    if (tid < 128) {
        int ksl = tid >> 6, lane = tid & 63;
        int ks = kt * 2 + ksl;
        int row16 = lane & 15;
        int kbase = ksl * 32 + (lane >> 4) * 8;
        unsigned short vals[8];
        if (row16 == 0) {
#pragma unroll
            for (int e = 0; e < 8; e++) vals[e] = f2b(spg[kbase + e]);
        } else if (row16 == 1) {
#pragma unroll
            for (int e = 0; e < 8; e++) vals[e] = 0x3F80;
        } else {
#pragma unroll
            for (int e = 0; e < 8; e++) vals[e] = 0;
        }
        uint2* d = (uint2*)(xpack + (((size_t)(b * 17 + 16) * 24 + ks) * 64 + lane) * 8);
        d[0] = *(uint2*)&vals[0];
        d[1] = *(uint2*)&vals[4];
    }
}

// ---------------------------------------------------------------------------
// kGram: the ~97 tiles kC consumes. grid (97, 4). Unchanged from r12.
// ---------------------------------------------------------------------------
__global__ __launch_bounds__(64) void kGram(const unsigned short* __restrict__ xpack,
                                            float* __restrict__ D) {
    int t = blockIdx.x, b = blockIdx.y;
    int it, jt;
    if (t < 64)      { it = t >> 3;  jt = 8 + (t & 7); }
    else if (t < 80) { it = t - 64;  jt = t - 64; }
    else             { it = t - 80;  jt = 16; }
    int lane = threadIdx.x, lq = lane >> 4, lr = lane & 15;
    const unsigned short* ar = xpack + ((size_t)(b * 17 + it) * 24 * 64 + lane) * 8;
    const unsigned short* wr = xpack + ((size_t)(b * 17 + jt) * 24 * 64 + lane) * 8;
    f32x4 acc = {0.f, 0.f, 0.f, 0.f};
#pragma unroll 8
    for (int s = 0; s < 24; s++) {
        short8 a = *(const short8*)(ar + (size_t)s * 512);
        short8 w = *(const short8*)(wr + (size_t)s * 512);
        acc = __builtin_amdgcn_mfma_f32_16x16x32_bf16(a, w, acc, 0, 0, 0);
    }
    float* Db = D + (size_t)b * DSTRIDE;
#pragma unroll
    for (int q = 0; q < 4; q++)
        Db[(size_t)(it * 16 + lq * 4 + q) * XROWS + jt * 16 + lr] = acc[q];
}

// ---------------------------------------------------------------------------
// kC: unchanged from r12.
// ---------------------------------------------------------------------------
__global__ __launch_bounds__(512, 6) void kC(const unsigned short* __restrict__ xb16,
                                             const float* __restrict__ ln_g,
                                             const float* __restrict__ ln_b,
                                             const unsigned short* __restrict__ rwb2,
                                             const float* __restrict__ rel_b,
                                             const float* __restrict__ D,
                                             const float* __restrict__ mask,
                                             float* __restrict__ out) {
    __shared__ __align__(16) unsigned char smem[49920];   // 32*780*2
    __shared__ float smu[32], srs[32];
    unsigned short (*zls)[780] = (unsigned short (*)[780])smem;
    int i = blockIdx.x, b = blockIdx.y, j0 = blockIdx.z * 32;
    int tid = threadIdx.x, lane = tid & 63, wave = tid >> 6;

    if (tid < 32) {
        const float* Db = D + (size_t)b * DSTRIDE;
        int vr = 128 + j0 + tid;
        float Su1 = Db[(size_t)i * XROWS + 257];
        float Su2 = Db[(size_t)i * XROWS + i];
        float up  = Db[(size_t)i * XROWS + 256];
        float Sp1 = Db[(size_t)256 * XROWS + 257];
        float Sp2 = Db[(size_t)256 * XROWS + 256];
        float Sv1 = Db[(size_t)vr * XROWS + 257];
        float Sv2 = Db[(size_t)vr * XROWS + vr];
        float Dij = Db[(size_t)i * XROWS + vr];
        float cvj = Db[(size_t)vr * XROWS + 256];
        float s1 = Su1 + Sp1 + Sv1;
        float s2 = Su2 + Sp2 + Sv2 + 2.f * (Dij + up + cvj);
        float mu = s1 * (1.f / 768.f);
        smu[tid] = mu;
        srs[tid] = rsqrtf(s2 * (1.f / 768.f) - mu * mu + LN_EPS);
    }
    const uint2* ur = (const uint2*)(xb16 + ((size_t)b * XROWS + i) * 768);
    const uint2* pr = (const uint2*)(xb16 + ((size_t)b * XROWS + 256) * 768);
    const float4* lg4 = (const float4*)ln_g;
    const float4* lb4 = (const float4*)ln_b;
    float4 t1[3], gg[3], bb[3];
#pragma unroll
    for (int s = 0; s < 3; s++) {
        int c = lane + 64 * s;
        float4 x = unpk4(ur[c]), y = unpk4(pr[c]);
        t1[s] = make_float4(x.x + y.x, x.y + y.y, x.z + y.z, x.w + y.w);
        gg[s] = lg4[c];
        bb[s] = lb4[c];
    }
    __syncthreads();

#pragma unroll
    for (int jj = 0; jj < 4; jj++) {
        int j = wave * 4 + jj;
        float mu = smu[j], rs = srs[j];
        const uint2* vr2 = (const uint2*)(xb16 + ((size_t)b * XROWS + 128 + j0 + j) * 768);
        uint2* zrow = (uint2*)&zls[j][0];
#pragma unroll
        for (int s = 0; s < 3; s++) {
            int c = lane + 64 * s;
            float4 vv = unpk4(vr2[c]);
            float A0 = rs * gg[s].x, A1 = rs * gg[s].y, A2 = rs * gg[s].z, A3 = rs * gg[s].w;
            float C0 = fmaf(-mu, A0, bb[s].x), C1 = fmaf(-mu, A1, bb[s].y);
            float C2 = fmaf(-mu, A2, bb[s].z), C3 = fmaf(-mu, A3, bb[s].w);
            float z0 = fmaf(t1[s].x + vv.x, A0, C0);
            float z1 = fmaf(t1[s].y + vv.y, A1, C1);
            float z2 = fmaf(t1[s].z + vv.z, A2, C2);
            float z3 = fmaf(t1[s].w + vv.w, A3, C3);
            z0 = fmaxf(z0, __expf(fminf(z0, 0.f)) - 1.f);
            z1 = fmaxf(z1, __expf(fminf(z1, 0.f)) - 1.f);
            z2 = fmaxf(z2, __expf(fminf(z2, 0.f)) - 1.f);
            z3 = fmaxf(z3, __expf(fminf(z3, 0.f)) - 1.f);
            uint2 o;
            o.x = (unsigned)f2b(z0) | ((unsigned)f2b(z1) << 16);
            o.y = (unsigned)f2b(z2) | ((unsigned)f2b(z3) << 16);
            zrow[c] = o;
        }
    }
    __syncthreads();

    int arow = lane & 31, ahi = lane >> 5;
    f32x16 acc = {0.f,0.f,0.f,0.f, 0.f,0.f,0.f,0.f, 0.f,0.f,0.f,0.f, 0.f,0.f,0.f,0.f};
    const unsigned short* bptr = rwb2 + ((size_t)(wave * 6) * 64 + lane) * 8;
#pragma unroll
    for (int st = 0; st < 6; st++) {
        int s = wave * 6 + st;
        short8 a  = *(const short8*)&zls[arow][s * 16 + ahi * 8];
        short8 bf = *(const short8*)(bptr + (size_t)st * 512);
        acc = __builtin_amdgcn_mfma_f32_32x32x16_bf16(a, bf, acc, 0, 0, 0);
    }
    __syncthreads();
    float* pf = (float*)smem;
#pragma unroll
    for (int r = 0; r < 16; r++) {
        int row = (r & 3) + 8 * (r >> 2) + 4 * ahi;
        pf[wave * 1024 + row * 32 + arow] = acc[r];
    }
    __syncthreads();

#pragma unroll
    for (int e0 = 0; e0 < 2; e0++) {
        int e = tid + e0 * 512;
        int row = e >> 5, col = e & 31;
        if (col < 24) {
            float v = 0.f;
#pragma unroll
            for (int w = 0; w < 8; w++) v += pf[w * 1024 + e];
            int jgl = j0 + row;
            float mval = mask[i * 4 + b] * mask[jgl * 4 + b];
            out[((size_t)(i * 128 + jgl) * 4 + b) * 24 + col] =
                mval / (1.f + __expf(-(v + rel_b[col])));
        }
    }
}

// ---------------------------------------------------------------------------
extern "C" void kernel_launch(void* const* d_in, const int* in_sizes, int n_in,
                              void* d_out, int out_size, void* d_ws, size_t ws_size,
                              hipStream_t stream) {
    const float* h_re    = (const float*)d_in[0];
    const float* h_share = (const float*)d_in[1];
    const float* mask    = (const float*)d_in[2];
    const float* r_w     = (const float*)d_in[3];
    const float* r_b     = (const float*)d_in[4];
    const float* hid_w   = (const float*)d_in[5];
    const float* hid_b   = (const float*)d_in[6];
    const float* ln_g    = (const float*)d_in[7];
    const float* ln_b    = (const float*)d_in[8];
    const float* rel_w   = (const float*)d_in[9];
    const float* rel_b   = (const float*)d_in[10];
    float* out = (float*)d_out;

    float* ws = (float*)d_ws;
    unsigned short* apack  = (unsigned short*)(ws);             // 393216 f
    unsigned short* wpackA = (unsigned short*)(ws + 393216);    // 589824 f
    unsigned short* wpackB = (unsigned short*)(ws + 983040);    // 589824 f
    unsigned short* xb16   = (unsigned short*)(ws + 1572864);   // 417792 f
    float*          D      = ws + 1990656;                      // 295936 f
    unsigned int*   gmax   = (unsigned int*)(ws + 2286592);     // 3072
    unsigned short* rwb2   = (unsigned short*)(ws + 2289664);   // 12288 f
    unsigned short* xpack  = (unsigned short*)(ws);             // aliases apack

    kConv<<<1552, 256, 0, stream>>>(h_re, h_share, r_w, hid_w, rel_w,
                                    apack, wpackA, wpackB, rwb2, gmax);
    kGemm<<<1152, 256, 0, stream>>>(apack, wpackA, wpackB, gmax, xb16);
    kPgPack<<<432, 256, 0, stream>>>(gmax, r_b, hid_w, hid_b, xb16, xpack);
    kGram<<<dim3(97, 4), 64, 0, stream>>>(xpack, D);
    kC<<<dim3(L, B, 4), 512, 0, stream>>>(xb16, ln_g, ln_b, rwb2, rel_b,
                                          D, mask, out);
}